// Round 8
// baseline (5473.878 us; speedup 1.0000x reference)
//
#include <hip/hip_runtime.h>
#include <hip/hip_bf16.h>

#define T_LEN 256
#define B_DIM 128
#define I_DIM 256
#define H_DIM 1024

typedef __attribute__((ext_vector_type(8))) short short8;
typedef __attribute__((ext_vector_type(4))) float f32x4;

// Subflags: g_sync[bq*16 + lj*2 + mt] = step count posted by epilogue wave
// (block lj, m-tile mt) of cluster bq. Re-zeroed by init_hT0 every replay.
__device__ unsigned g_sync[256];

// RNE float->bf16 (self-contained; inputs here are never NaN)
static __device__ __forceinline__ unsigned short f2bf(float f) {
  unsigned u = __float_as_uint(f);
  return (unsigned short)((u + 0x7fffu + ((u >> 16) & 1u)) >> 16);
}
static __device__ __forceinline__ float bf2f(unsigned short h) {
  return __uint_as_float((unsigned)h << 16);
}

// ---------------------------------------------------------------------------
// Phase 1a (fallback): x_proj GEMM fp32 (proven, used when ws is small).
// ---------------------------------------------------------------------------
__global__ __launch_bounds__(256) void xproj_gemm(
    const float* __restrict__ A, const float* __restrict__ W,
    const float* __restrict__ bias, float* __restrict__ C) {
  __shared__ float As[64][33];
  __shared__ float Ws[64][33];

  const int tid = threadIdx.x;
  const int m0 = blockIdx.y * 64;
  const int n0 = blockIdx.x * 64;
  const int ty = tid >> 4;
  const int tx = tid & 15;
  const int r   = tid >> 3;
  const int c4  = (tid & 7) << 2;

  float acc[4][4] = {};

  for (int kc = 0; kc < I_DIM; kc += 32) {
#pragma unroll
    for (int p = 0; p < 2; ++p) {
      const int rr = r + p * 32;
      const float4 a = *(const float4*)(A + (size_t)(m0 + rr) * I_DIM + kc + c4);
      As[rr][c4 + 0] = a.x; As[rr][c4 + 1] = a.y;
      As[rr][c4 + 2] = a.z; As[rr][c4 + 3] = a.w;
      const float4 w = *(const float4*)(W + (size_t)(n0 + rr) * I_DIM + kc + c4);
      Ws[rr][c4 + 0] = w.x; Ws[rr][c4 + 1] = w.y;
      Ws[rr][c4 + 2] = w.z; Ws[rr][c4 + 3] = w.w;
    }
    __syncthreads();
#pragma unroll
    for (int k = 0; k < 32; ++k) {
      float av[4], wv[4];
#pragma unroll
      for (int i = 0; i < 4; ++i) av[i] = As[ty * 4 + i][k];
#pragma unroll
      for (int j = 0; j < 4; ++j) wv[j] = Ws[tx * 4 + j][k];
#pragma unroll
      for (int i = 0; i < 4; ++i)
#pragma unroll
        for (int j = 0; j < 4; ++j)
          acc[i][j] = fmaf(av[i], wv[j], acc[i][j]);
    }
    __syncthreads();
  }

  const float4 bv = *(const float4*)(bias + n0 + tx * 4);
#pragma unroll
  for (int i = 0; i < 4; ++i) {
    float4 o;
    o.x = acc[i][0] + bv.x;
    o.y = acc[i][1] + bv.y;
    o.z = acc[i][2] + bv.z;
    o.w = acc[i][3] + bv.w;
    *(float4*)(C + (size_t)(m0 + ty * 4 + i) * H_DIM + n0 + tx * 4) = o;
  }
}

// ---------------------------------------------------------------------------
// Phase 1b: x_proj via split-bf16 MFMA (r6-proven, absmax unchanged).
// ---------------------------------------------------------------------------
__global__ __launch_bounds__(256) void cvt_hi_lo(
    const float* __restrict__ X, unsigned short* __restrict__ Xh,
    unsigned short* __restrict__ Xl) {
  const int i4 = blockIdx.x * 256 + threadIdx.x;     // one float4 per thread
  const float4 x = ((const float4*)X)[i4];
  ushort4 h, l;
  h.x = f2bf(x.x); l.x = f2bf(x.x - bf2f(h.x));
  h.y = f2bf(x.y); l.y = f2bf(x.y - bf2f(h.y));
  h.z = f2bf(x.z); l.z = f2bf(x.z - bf2f(h.z));
  h.w = f2bf(x.w); l.w = f2bf(x.w - bf2f(h.w));
  ((ushort4*)Xh)[i4] = h;
  ((ushort4*)Xl)[i4] = l;
}

__global__ __launch_bounds__(256) void xproj_mfma(
    const unsigned short* __restrict__ Ah, const unsigned short* __restrict__ Al,
    const unsigned short* __restrict__ Wh, const unsigned short* __restrict__ Wl,
    const float* __restrict__ bias, float* __restrict__ C) {
  const int tid  = threadIdx.x;
  const int wv   = tid >> 6;
  const int lane = tid & 63;
  const int ln   = lane & 15;
  const int q    = lane >> 4;
  const int mw   = wv >> 1;                 // 0..1
  const int nw   = wv & 1;                  // 0..1
  const int m0   = blockIdx.y * 128 + mw * 64;
  const int n0   = blockIdx.x * 64  + nw * 32;

  f32x4 acc[4][2] = {};

#pragma unroll
  for (int kc = 0; kc < 8; ++kc) {          // K = 256 = 8 x 32
    const int ko = kc * 32 + q * 8;
    short8 afh[4], afl[4], wfh[2], wfl[2];
#pragma unroll
    for (int fm = 0; fm < 4; ++fm) {
      const size_t off = (size_t)(m0 + fm * 16 + ln) * I_DIM + ko;
      afh[fm] = *(const short8*)(Ah + off);
      afl[fm] = *(const short8*)(Al + off);
    }
#pragma unroll
    for (int fn = 0; fn < 2; ++fn) {
      const size_t off = (size_t)(n0 + fn * 16 + ln) * I_DIM + ko;
      wfh[fn] = *(const short8*)(Wh + off);
      wfl[fn] = *(const short8*)(Wl + off);
    }
#pragma unroll
    for (int fm = 0; fm < 4; ++fm)
#pragma unroll
      for (int fn = 0; fn < 2; ++fn) {
        acc[fm][fn] = __builtin_amdgcn_mfma_f32_16x16x32_bf16(afh[fm], wfh[fn], acc[fm][fn], 0, 0, 0);
        acc[fm][fn] = __builtin_amdgcn_mfma_f32_16x16x32_bf16(afh[fm], wfl[fn], acc[fm][fn], 0, 0, 0);
        acc[fm][fn] = __builtin_amdgcn_mfma_f32_16x16x32_bf16(afl[fm], wfh[fn], acc[fm][fn], 0, 0, 0);
      }
  }

  // D layout: col (j) = lane&15, row (m) = (lane>>4)*4 + reg.
#pragma unroll
  for (int fn = 0; fn < 2; ++fn) {
    const int j = n0 + fn * 16 + ln;
    const float bj = bias[j];
#pragma unroll
    for (int fm = 0; fm < 4; ++fm)
#pragma unroll
      for (int r = 0; r < 4; ++r)
        C[(size_t)(m0 + fm * 16 + q * 4 + r) * H_DIM + j] = acc[fm][fn][r] + bj;
  }
}

// ---------------------------------------------------------------------------
// One-time converts: W_hh -> bf16 [j][k]; hT0 -> bf16 broadcast of h0.
// init_hT0 also re-zeroes the sync flags.
// ---------------------------------------------------------------------------
__global__ __launch_bounds__(256) void cvt_w_bf16(
    const float* __restrict__ W, unsigned short* __restrict__ Wb) {
  const int i4 = blockIdx.x * 256 + threadIdx.x;
  const float4 w = ((const float4*)W)[i4];
  ushort4 o;
  o.x = f2bf(w.x); o.y = f2bf(w.y); o.z = f2bf(w.z); o.w = f2bf(w.w);
  ((ushort4*)Wb)[i4] = o;
}

__global__ __launch_bounds__(256) void init_hT0(
    const float* __restrict__ h0, unsigned short* __restrict__ hT) {
  const int idx = blockIdx.x * 256 + threadIdx.x;    // [0, 131072)
  hT[idx] = f2bf(h0[idx & (H_DIM - 1)]);
  if (blockIdx.x == 0) g_sync[threadIdx.x] = 0u;
}

// ---------------------------------------------------------------------------
// Phase 2: persistent cooperative kernel, round-8 "fat block" layout.
// Grid 32 = 4 b-quarter clusters x 8 blocks (128 j each). Block 512 thr =
// 8 waves: wave w -> m-tile mt=w&1 (16 of the 32 b) x k-quarter kq=w>>1
// (256 k). Waves cover the block's h need EXACTLY once -> cluster h traffic
// drops 8 MB/step (r5-r7, 128 thin blocks) -> 2 MB/step: that redundant
// coherent-L3 read stream was the hidden floor.
//
// Step t:
//   B: __syncthreads (release; drains everything incl. prev x loads)
//   C: 8x sc0sc1 h loads per wave, vmcnt(0)
//   D: 64 MFMA, W streamed from global L2 (opaque base per step via empty
//      asm -> defeats the LICM-hoist->spill of r5/r6; no r7 LDS-W latency)
//   kq>0 waves write partials to red[][]; E: __syncthreads
//   F: kq==0 waves: final sum, compute, 32 WT h-stores, vmcnt(0), POST
//      subflag -- then (off the flag path) xio fp32 stores + x[t+1] loads,
//      which drain at next B under the poll window.
//      wave 2 (kq=1): polls all 16 cluster subflags >= t+1 (one 64B line),
//      overlapping the epilogue; barrier B broadcasts the release.
// Safety: subflag(lj,mt) >= t implies that block passed E(t-1) (all 8 waves
// done reading parity (t-1)&1) and its h[t] WT-stores are drained; writer
// overwrites parity (t+1)&1 only after B(t) <- poller saw ALL cluster
// subflags >= t. Coherence: WT relaxed-agent stores + sc0sc1 loads (r4-r7).
// ---------------------------------------------------------------------------
__global__ __launch_bounds__(512, 1) void rnn_persist(
    unsigned short* __restrict__ hT,            // ping-pong; parity0 = bf16(h0)
    const unsigned short* __restrict__ Wb,      // [1024][1024] bf16
    const float* __restrict__ b_hh,
    const float* __restrict__ h0,
    float* __restrict__ out)                    // [T][B][H]: in x_proj, out h_t
{
  __shared__ float red[2][3][16][132];   // [mt][kq-1][b_local][j_local], 2-way-free pad

  const int tid  = threadIdx.x;
  const int wv   = tid >> 6;         // 0..7
  const int lane = tid & 63;
  const int ln   = lane & 15;        // A: b-row / B: j-row / D: j-col
  const int q    = lane >> 4;        // 0..3

  const int bid = blockIdx.x;        // 0..31
  const int bq  = bid >> 3;          // cluster (batch quarter)
  const int lj  = bid & 7;           // block in cluster (128 j)
  const int j0  = lj * 128;
  const int mt  = wv & 1;            // m-tile
  const int kq  = wv >> 1;           // k-quarter 0..3
  const int b0  = bq * 32 + mt * 16;

  const size_t HT = (size_t)B_DIM * H_DIM;     // 131072
  const unsigned short* __restrict__ ha0 =
      hT + (size_t)(b0 + ln) * H_DIM + kq * 256 + q * 8;
  const unsigned short* __restrict__ ha1 = ha0 + HT;
  const unsigned short* __restrict__ wbase0 =
      Wb + (size_t)(j0 + ln) * H_DIM + kq * 256 + q * 8;

  const bool epi = (kq == 0);        // waves 0,1: epilogue owners

  float bj[8], hcur[8][4], xcur[8][4];
  if (epi) {
#pragma unroll
    for (int jf = 0; jf < 8; ++jf) {
      bj[jf] = b_hh[j0 + jf * 16 + ln];
      const float h0j = h0[j0 + jf * 16 + ln];
#pragma unroll
      for (int r = 0; r < 4; ++r) {
        hcur[jf][r] = h0j;
        xcur[jf][r] = out[(size_t)(b0 + q * 4 + r) * H_DIM + j0 + jf * 16 + ln];
      }
    }
  }

  unsigned* myflag = &g_sync[bq * 16 + lj * 2 + mt];
  unsigned* pollw  = &g_sync[bq * 16 + ln];     // ln 0..15 cover the 16 subflags

  for (int t = 0; t < T_LEN; ++t) {
    __syncthreads();   // B: release for step t; drains prev x loads/stores

    // Opaque W base: blocks LICM from hoisting 64 t-invariant loads (spill).
    const unsigned short* wb = wbase0;
    asm volatile("" : "+v"(wb));

    // C: h fragments — 8 coherent 16B loads (wave's exact (mt,kq) chunk).
    const unsigned short* __restrict__ ha = (t & 1) ? ha1 : ha0;
    short8 hfrag[8];
#pragma unroll
    for (int kc = 0; kc < 8; ++kc) {
      asm volatile("global_load_dwordx4 %0, %1, off offset:%2 sc0 sc1"
                   : "=&v"(hfrag[kc]) : "v"(ha), "i"(kc * 64));
    }
    asm volatile("s_waitcnt vmcnt(0)" ::: "memory");
    __builtin_amdgcn_sched_barrier(0);   // rule #18

    // D: 8 jf x 8 kc MFMA, W streamed from L2.
    f32x4 acc[8];
#pragma unroll
    for (int jf = 0; jf < 8; ++jf) acc[jf] = (f32x4){0.f, 0.f, 0.f, 0.f};
#pragma unroll
    for (int kc = 0; kc < 8; ++kc) {
#pragma unroll
      for (int jf = 0; jf < 8; ++jf) {
        const short8 wf = *(const short8*)(wb + (size_t)jf * 16 * H_DIM + kc * 32);
        acc[jf] = __builtin_amdgcn_mfma_f32_16x16x32_bf16(hfrag[kc], wf, acc[jf], 0, 0, 0);
      }
    }

    // Partials: D layout j_col = ln, b_row = q*4 + r.
    if (!epi) {
#pragma unroll
      for (int jf = 0; jf < 8; ++jf)
#pragma unroll
        for (int r = 0; r < 4; ++r)
          red[mt][kq - 1][q * 4 + r][jf * 16 + ln] = acc[jf][r];
    }
    __syncthreads();   // E: partials visible to epilogue waves

    if (epi) {
      unsigned short* __restrict__ hnext = hT + (size_t)((t + 1) & 1) * HT;
      float* __restrict__ xio_t = out + (size_t)t * HT;
      float v[8][4];
#pragma unroll
      for (int jf = 0; jf < 8; ++jf)
#pragma unroll
        for (int r = 0; r < 4; ++r) {
          const int jl = jf * 16 + ln;
          const int bl = q * 4 + r;
          const float rec = acc[jf][r] + red[mt][0][bl][jl] +
                            red[mt][1][bl][jl] + red[mt][2][bl][jl];
          float x = 0.9f * hcur[jf][r] + 0.1f * (rec + bj[jf] + xcur[jf][r]);
          x = x > 0.f ? x : 0.f;
          v[jf][r] = x;
          hcur[jf][r] = x;
          __hip_atomic_store(&hnext[(size_t)(b0 + bl) * H_DIM + j0 + jl],
                             f2bf(x), __ATOMIC_RELAXED, __HIP_MEMORY_SCOPE_AGENT);
        }
      // Flag path: only the 32 WT h-stores drain before posting.
      asm volatile("s_waitcnt vmcnt(0)" ::: "memory");
      __builtin_amdgcn_sched_barrier(0);
      if (lane == 0)
        __hip_atomic_store(myflag, (unsigned)(t + 1), __ATOMIC_RELAXED,
                           __HIP_MEMORY_SCOPE_AGENT);
      // Off the flag path: fp32 outputs + next step's x_proj loads.
      // Both drain at the next B, hidden under the poll window.
      const int tn = (t + 1 < T_LEN) ? t + 1 : t;
      const float* __restrict__ xnp = out + (size_t)tn * HT;
#pragma unroll
      for (int jf = 0; jf < 8; ++jf)
#pragma unroll
        for (int r = 0; r < 4; ++r) {
          const size_t oidx = (size_t)(b0 + q * 4 + r) * H_DIM + j0 + jf * 16 + ln;
          xio_t[oidx] = v[jf][r];
          xcur[jf][r] = xnp[oidx];   // plain cached load; used next step
        }
    } else if (wv == 2 && t + 1 < T_LEN) {
      // Poller: one wave per block watches all 16 cluster subflags (one line).
      const unsigned tgt = (unsigned)(t + 1);
      for (;;) {
        unsigned fv;
        asm volatile("global_load_dword %0, %1, off sc0 sc1\n\t"
                     "s_waitcnt vmcnt(0)"
                     : "=v"(fv) : "v"(pollw) : "memory");
        if (__all((int)fv >= (int)tgt)) break;
        __builtin_amdgcn_s_sleep(1);
      }
    }
  }
}

// ---------------------------------------------------------------------------
extern "C" void kernel_launch(void* const* d_in, const int* in_sizes, int n_in,
                              void* d_out, int out_size, void* d_ws, size_t ws_size,
                              hipStream_t stream) {
  const float* input = (const float*)d_in[0];
  const float* W_in  = (const float*)d_in[1];
  const float* b_in  = (const float*)d_in[2];
  const float* W_hh  = (const float*)d_in[3];
  const float* b_hh  = (const float*)d_in[4];
  const float* h0    = (const float*)d_in[5];
  float* out = (float*)d_out;

  // ws layout (bytes):
  //   [0,  2M)   Wb   bf16 [1024][1024]
  //   [2M, 2.5M) hT   ping-pong 2 x 256 KB
  //   [2.5M,3M)  Wih  bf16-hi W_in ; [3M,3.5M) Wil bf16-lo
  //   [4M, 20M)  Ah   bf16-hi input ; [20M,36M) Al bf16-lo
  char* ws = (char*)d_ws;
  unsigned short* Wb  = (unsigned short*)ws;
  unsigned short* hT  = (unsigned short*)(ws + (2u << 20));
  unsigned short* Wih = (unsigned short*)(ws + (5u << 19));
  unsigned short* Wil = (unsigned short*)(ws + (3u << 20));
  unsigned short* Ah  = (unsigned short*)(ws + (4u << 20));
  unsigned short* Al  = (unsigned short*)(ws + (20u << 20));

  cvt_w_bf16<<<(H_DIM * H_DIM / 4) / 256, 256, 0, stream>>>(W_hh, Wb);
  init_hT0<<<(B_DIM * H_DIM) / 256, 256, 0, stream>>>(h0, hT);

  if (ws_size >= (36u << 20)) {
    cvt_hi_lo<<<(T_LEN * B_DIM * I_DIM / 4) / 256, 256, 0, stream>>>(input, Ah, Al);
    cvt_hi_lo<<<(H_DIM * I_DIM / 4) / 256, 256, 0, stream>>>(W_in, Wih, Wil);
    dim3 g1(H_DIM / 64, (T_LEN * B_DIM) / 128);
    xproj_mfma<<<g1, 256, 0, stream>>>(Ah, Al, Wih, Wil, b_in, out);
  } else {
    dim3 g1(H_DIM / 64, (T_LEN * B_DIM) / 64);
    xproj_gemm<<<g1, 256, 0, stream>>>(input, W_in, b_in, out);
  }

  {
    unsigned short* hT_ = hT;
    const unsigned short* Wb_ = Wb;
    const float* bhh_ = b_hh;
    const float* h0_ = h0;
    float* out_ = out;
    void* pargs[5] = {(void*)&hT_, (void*)&Wb_, (void*)&bhh_, (void*)&h0_, (void*)&out_};
    hipLaunchCooperativeKernel((const void*)rnn_persist, dim3(32), dim3(512),
                               pargs, 0, stream);
  }
}

// Round 9
// 1806.652 us; speedup vs baseline: 3.0298x; 3.0298x over previous
//
#include <hip/hip_runtime.h>
#include <hip/hip_bf16.h>

#define T_LEN 256
#define B_DIM 128
#define I_DIM 256
#define H_DIM 1024

typedef __attribute__((ext_vector_type(8))) short short8;
typedef __attribute__((ext_vector_type(4))) float f32x4;

// Subflags: g_sync[bq*64 + lj*2 + mt] = step count posted by epilogue wave mt
// of block lj in cluster bq. Clusters 256B apart. Re-zeroed by init_hT0.
__device__ unsigned g_sync[256];

// RNE float->bf16 (self-contained; inputs here are never NaN)
static __device__ __forceinline__ unsigned short f2bf(float f) {
  unsigned u = __float_as_uint(f);
  return (unsigned short)((u + 0x7fffu + ((u >> 16) & 1u)) >> 16);
}
static __device__ __forceinline__ float bf2f(unsigned short h) {
  return __uint_as_float((unsigned)h << 16);
}

// ---------------------------------------------------------------------------
// Phase 1a (fallback): x_proj GEMM fp32 (proven, used when ws is small).
// ---------------------------------------------------------------------------
__global__ __launch_bounds__(256) void xproj_gemm(
    const float* __restrict__ A, const float* __restrict__ W,
    const float* __restrict__ bias, float* __restrict__ C) {
  __shared__ float As[64][33];
  __shared__ float Ws[64][33];

  const int tid = threadIdx.x;
  const int m0 = blockIdx.y * 64;
  const int n0 = blockIdx.x * 64;
  const int ty = tid >> 4;
  const int tx = tid & 15;
  const int r   = tid >> 3;
  const int c4  = (tid & 7) << 2;

  float acc[4][4] = {};

  for (int kc = 0; kc < I_DIM; kc += 32) {
#pragma unroll
    for (int p = 0; p < 2; ++p) {
      const int rr = r + p * 32;
      const float4 a = *(const float4*)(A + (size_t)(m0 + rr) * I_DIM + kc + c4);
      As[rr][c4 + 0] = a.x; As[rr][c4 + 1] = a.y;
      As[rr][c4 + 2] = a.z; As[rr][c4 + 3] = a.w;
      const float4 w = *(const float4*)(W + (size_t)(n0 + rr) * I_DIM + kc + c4);
      Ws[rr][c4 + 0] = w.x; Ws[rr][c4 + 1] = w.y;
      Ws[rr][c4 + 2] = w.z; Ws[rr][c4 + 3] = w.w;
    }
    __syncthreads();
#pragma unroll
    for (int k = 0; k < 32; ++k) {
      float av[4], wv[4];
#pragma unroll
      for (int i = 0; i < 4; ++i) av[i] = As[ty * 4 + i][k];
#pragma unroll
      for (int j = 0; j < 4; ++j) wv[j] = Ws[tx * 4 + j][k];
#pragma unroll
      for (int i = 0; i < 4; ++i)
#pragma unroll
        for (int j = 0; j < 4; ++j)
          acc[i][j] = fmaf(av[i], wv[j], acc[i][j]);
    }
    __syncthreads();
  }

  const float4 bv = *(const float4*)(bias + n0 + tx * 4);
#pragma unroll
  for (int i = 0; i < 4; ++i) {
    float4 o;
    o.x = acc[i][0] + bv.x;
    o.y = acc[i][1] + bv.y;
    o.z = acc[i][2] + bv.z;
    o.w = acc[i][3] + bv.w;
    *(float4*)(C + (size_t)(m0 + ty * 4 + i) * H_DIM + n0 + tx * 4) = o;
  }
}

// ---------------------------------------------------------------------------
// Phase 1b: x_proj via split-bf16 MFMA (r6-proven, absmax unchanged).
// ---------------------------------------------------------------------------
__global__ __launch_bounds__(256) void cvt_hi_lo(
    const float* __restrict__ X, unsigned short* __restrict__ Xh,
    unsigned short* __restrict__ Xl) {
  const int i4 = blockIdx.x * 256 + threadIdx.x;     // one float4 per thread
  const float4 x = ((const float4*)X)[i4];
  ushort4 h, l;
  h.x = f2bf(x.x); l.x = f2bf(x.x - bf2f(h.x));
  h.y = f2bf(x.y); l.y = f2bf(x.y - bf2f(h.y));
  h.z = f2bf(x.z); l.z = f2bf(x.z - bf2f(h.z));
  h.w = f2bf(x.w); l.w = f2bf(x.w - bf2f(h.w));
  ((ushort4*)Xh)[i4] = h;
  ((ushort4*)Xl)[i4] = l;
}

__global__ __launch_bounds__(256) void xproj_mfma(
    const unsigned short* __restrict__ Ah, const unsigned short* __restrict__ Al,
    const unsigned short* __restrict__ Wh, const unsigned short* __restrict__ Wl,
    const float* __restrict__ bias, float* __restrict__ C) {
  const int tid  = threadIdx.x;
  const int wv   = tid >> 6;
  const int lane = tid & 63;
  const int ln   = lane & 15;
  const int q    = lane >> 4;
  const int mw   = wv >> 1;                 // 0..1
  const int nw   = wv & 1;                  // 0..1
  const int m0   = blockIdx.y * 128 + mw * 64;
  const int n0   = blockIdx.x * 64  + nw * 32;

  f32x4 acc[4][2] = {};

#pragma unroll
  for (int kc = 0; kc < 8; ++kc) {          // K = 256 = 8 x 32
    const int ko = kc * 32 + q * 8;
    short8 afh[4], afl[4], wfh[2], wfl[2];
#pragma unroll
    for (int fm = 0; fm < 4; ++fm) {
      const size_t off = (size_t)(m0 + fm * 16 + ln) * I_DIM + ko;
      afh[fm] = *(const short8*)(Ah + off);
      afl[fm] = *(const short8*)(Al + off);
    }
#pragma unroll
    for (int fn = 0; fn < 2; ++fn) {
      const size_t off = (size_t)(n0 + fn * 16 + ln) * I_DIM + ko;
      wfh[fn] = *(const short8*)(Wh + off);
      wfl[fn] = *(const short8*)(Wl + off);
    }
#pragma unroll
    for (int fm = 0; fm < 4; ++fm)
#pragma unroll
      for (int fn = 0; fn < 2; ++fn) {
        acc[fm][fn] = __builtin_amdgcn_mfma_f32_16x16x32_bf16(afh[fm], wfh[fn], acc[fm][fn], 0, 0, 0);
        acc[fm][fn] = __builtin_amdgcn_mfma_f32_16x16x32_bf16(afh[fm], wfl[fn], acc[fm][fn], 0, 0, 0);
        acc[fm][fn] = __builtin_amdgcn_mfma_f32_16x16x32_bf16(afl[fm], wfh[fn], acc[fm][fn], 0, 0, 0);
      }
  }

  // D layout: col (j) = lane&15, row (m) = (lane>>4)*4 + reg.
#pragma unroll
  for (int fn = 0; fn < 2; ++fn) {
    const int j = n0 + fn * 16 + ln;
    const float bj = bias[j];
#pragma unroll
    for (int fm = 0; fm < 4; ++fm)
#pragma unroll
      for (int r = 0; r < 4; ++r)
        C[(size_t)(m0 + fm * 16 + q * 4 + r) * H_DIM + j] = acc[fm][fn][r] + bj;
  }
}

// ---------------------------------------------------------------------------
// One-time converts: W_hh -> bf16 [j][k]; hT0 -> bf16 broadcast of h0.
// init_hT0 also re-zeroes the sync flags.
// ---------------------------------------------------------------------------
__global__ __launch_bounds__(256) void cvt_w_bf16(
    const float* __restrict__ W, unsigned short* __restrict__ Wb) {
  const int i4 = blockIdx.x * 256 + threadIdx.x;
  const float4 w = ((const float4*)W)[i4];
  ushort4 o;
  o.x = f2bf(w.x); o.y = f2bf(w.y); o.z = f2bf(w.z); o.w = f2bf(w.w);
  ((ushort4*)Wb)[i4] = o;
}

__global__ __launch_bounds__(256) void init_hT0(
    const float* __restrict__ h0, unsigned short* __restrict__ hT) {
  const int idx = blockIdx.x * 256 + threadIdx.x;    // [0, 131072)
  hT[idx] = f2bf(h0[idx & (H_DIM - 1)]);
  if (blockIdx.x == 0) g_sync[threadIdx.x] = 0u;
}

// ---------------------------------------------------------------------------
// Phase 2: persistent cooperative kernel — round-9: r6 skeleton (128 thin
// blocks = 4 clusters x 32 j-tiles of 32 j; 256 thr) with the measured
// defects fixed:
//   * wave = k-QUARTER kq (0..3), both m-tiles per wave:
//       W/wave = 32j x 256k = 16 KB = 64 VGPR (wfrag[2][8]) -> NO spill
//       (r6's 128-VGPR wfrag spilled to scratch: VGPR_Count=124).
//       h/wave = 32b x 256k (hfrag[2][8]); zero W/h duplication in a block.
//   * load order per step: poll -> 16 h sc0sc1 loads -> 8 x[t+1] plain loads
//     (asm-ordered) -> s_waitcnt vmcnt(8): in-order retirement means this
//     waits exactly the h-loads; x[t+1] stays in flight under the MFMA and
//     a full step (r6 issued x BEFORE the poll, whose vmcnt(0) drained the
//     cold-HBM x serially on the critical path).
//   * epilogue split by m-tile across waves 0/1, each posts subflag
//     g_sync[bq*64+lj*2+mt]; consumer wave kq polls its 8 producer blocks
//     (lj in [kq*8,kq*8+8)) x both subflags = 16 words = one 64B line.
//   * ONE __syncthreads per step; red[] parity-double-buffered so waves 2/3
//     may run ahead into step t+1's MFMA while 0/1 finish epilogue(t).
// Ping-pong safety: union of the block's 4 poll sets = all 32 blocks x both
// subflags >= t, joined by the barrier before the epilogue overwrites parity
// (t+1)&1. flag(mt)>=t  =>  that block passed barrier(t-1) (done reading
// parity (t+1)&1) and its h(t) WT-stores are drained.
// Coherence (r4-r8 proven): h WT relaxed-agent stores + sc0sc1 loads; no
// cache maintenance anywhere.
// ---------------------------------------------------------------------------
__global__ __launch_bounds__(256, 1) void rnn_persist(
    unsigned short* __restrict__ hT,            // ping-pong; parity0 = bf16(h0)
    const unsigned short* __restrict__ Wb,      // [1024][1024] bf16
    const float* __restrict__ b_hh,
    const float* __restrict__ h0,
    float* __restrict__ out)                    // [T][B][H]: in x_proj, out h_t
{
  // red[par][slot][mt][b_local][j_local]; slots: kq0->[0][1], kq1->[0][0],
  // kq2->[1][*], kq3->[2][*]. 25.3 KB.
  __shared__ float red[2][3][2][16][33];

  const int tid  = threadIdx.x;
  const int kq   = tid >> 6;         // wave = k-quarter
  const int lane = tid & 63;
  const int ln   = lane & 15;        // A: b-row / B: j-row / D: j-col
  const int q    = lane >> 4;        // 0..3

  const int bid = blockIdx.x;
  const int bq  = bid >> 5;          // cluster (batch quarter)
  const int lj  = bid & 31;          // j-tile within cluster
  const int j0  = lj * 32;
  const int mt  = kq;                // epilogue m-tile for waves 0,1

  // W fragments: rows j0+jf*16+ln, cols kq*256 + kc*32 + q*8. 64 VGPR.
  short8 wfrag[2][8];
#pragma unroll
  for (int jf = 0; jf < 2; ++jf) {
    const short8* wp = (const short8*)(Wb + (size_t)(j0 + jf * 16 + ln) * H_DIM
                                       + kq * 256 + q * 8);
#pragma unroll
    for (int kc = 0; kc < 8; ++kc) wfrag[jf][kc] = wp[kc * 4];
  }

  const size_t HT = (size_t)B_DIM * H_DIM;     // 131072
  const size_t o_m0 = (size_t)(bq * 32 + ln) * H_DIM + kq * 256 + q * 8;
  const size_t o_m1 = o_m0 + (size_t)16 * H_DIM;

  const bool epi = (kq < 2);
  float bj2[2], hcur[2][4], xcur[2][4];
  size_t obase = 0;
  if (epi) {
    obase = (size_t)(bq * 32 + mt * 16 + q * 4) * H_DIM + j0 + ln;
#pragma unroll
    for (int jf = 0; jf < 2; ++jf) {
      bj2[jf] = b_hh[j0 + jf * 16 + ln];
      const float h0j = h0[j0 + jf * 16 + ln];
#pragma unroll
      for (int r = 0; r < 4; ++r) {
        hcur[jf][r] = h0j;
        xcur[jf][r] = out[obase + (size_t)r * H_DIM + jf * 16];
      }
    }
  }

  unsigned* pollp  = &g_sync[bq * 64 + kq * 16 + ln];
  unsigned* myflag = &g_sync[bq * 64 + lj * 2 + mt];   // used by epi waves

  asm volatile("s_waitcnt vmcnt(0)" ::: "memory");   // clean vmcnt slate

  for (int t = 0; t < T_LEN; ++t) {
    const int par = t & 1;
    // Pin W in registers (in-loop keep-alive; ~200 total VGPR -> no spill).
#pragma unroll
    for (int jf = 0; jf < 2; ++jf)
#pragma unroll
      for (int kc = 0; kc < 8; ++kc) asm volatile("" : "+v"(wfrag[jf][kc]));

    // ---- poll this wave's 16 producer subflags (one 64B line) ----
    if (t > 0) {
      const unsigned tgt = (unsigned)t;
      for (;;) {
        unsigned fv;
        asm volatile("global_load_dword %0, %1, off sc0 sc1\n\t"
                     "s_waitcnt vmcnt(0)"
                     : "=v"(fv) : "v"(pollp) : "memory");
        if (__all((int)fv >= (int)tgt)) break;
        __builtin_amdgcn_s_sleep(1);
      }
    }
    __builtin_amdgcn_sched_barrier(0);

    // ---- 16 coherent h loads (issued first = drained by vmcnt(8)) ----
    const unsigned short* hpar = hT + (size_t)par * HT;
    const unsigned short* p0 = hpar + o_m0;
    const unsigned short* p1 = hpar + o_m1;
    short8 hfrag[2][8];
#pragma unroll
    for (int kc = 0; kc < 8; ++kc)
      asm volatile("global_load_dwordx4 %0, %1, off offset:%2 sc0 sc1"
                   : "=&v"(hfrag[0][kc]) : "v"(p0), "i"(kc * 64));
#pragma unroll
    for (int kc = 0; kc < 8; ++kc)
      asm volatile("global_load_dwordx4 %0, %1, off offset:%2 sc0 sc1"
                   : "=&v"(hfrag[1][kc]) : "v"(p1), "i"(kc * 64));

    // ---- x[t+1] prefetch (epi waves): stays in flight under the MFMA ----
    float xnf[2][4];
    if (epi) {
      const int tn = (t + 1 < T_LEN) ? t + 1 : t;
      const float* xb = out + (size_t)tn * HT;
#pragma unroll
      for (int jf = 0; jf < 2; ++jf)
#pragma unroll
        for (int r = 0; r < 4; ++r) {
          const float* p = xb + obase + (size_t)r * H_DIM + jf * 16;
          asm volatile("global_load_dword %0, %1, off"
                       : "=&v"(xnf[jf][r]) : "v"(p));
        }
      asm volatile("s_waitcnt vmcnt(8)" ::: "memory");  // h done, x in flight
    } else {
      asm volatile("s_waitcnt vmcnt(0)" ::: "memory");
    }
    __builtin_amdgcn_sched_barrier(0);   // rule #18

    // ---- MFMA: 2 mt x 2 jf x 8 kc = 32, four independent chains ----
    f32x4 acc[2][2];
#pragma unroll
    for (int m = 0; m < 2; ++m)
#pragma unroll
      for (int jf = 0; jf < 2; ++jf) acc[m][jf] = (f32x4){0.f, 0.f, 0.f, 0.f};
#pragma unroll
    for (int kc = 0; kc < 8; ++kc)
#pragma unroll
      for (int m = 0; m < 2; ++m)
#pragma unroll
        for (int jf = 0; jf < 2; ++jf)
          acc[m][jf] = __builtin_amdgcn_mfma_f32_16x16x32_bf16(
              hfrag[m][kc], wfrag[jf][kc], acc[m][jf], 0, 0, 0);

    // ---- partial dump (D layout: j_col = ln, b_row = q*4 + r) ----
    if (kq == 0) {
#pragma unroll
      for (int jf = 0; jf < 2; ++jf)
#pragma unroll
        for (int r = 0; r < 4; ++r)
          red[par][0][1][q * 4 + r][jf * 16 + ln] = acc[1][jf][r];
    } else if (kq == 1) {
#pragma unroll
      for (int jf = 0; jf < 2; ++jf)
#pragma unroll
        for (int r = 0; r < 4; ++r)
          red[par][0][0][q * 4 + r][jf * 16 + ln] = acc[0][jf][r];
    } else {
#pragma unroll
      for (int m = 0; m < 2; ++m)
#pragma unroll
        for (int jf = 0; jf < 2; ++jf)
#pragma unroll
          for (int r = 0; r < 4; ++r)
            red[par][kq - 1][m][q * 4 + r][jf * 16 + ln] = acc[m][jf][r];
    }
    __syncthreads();   // ONE barrier/step; also the ping-pong union join

    if (epi) {
      // Epilogue for m-tile mt==kq (static acc index via branch).
      unsigned short* hnext = hT + (size_t)((t + 1) & 1) * HT;
      float* xio_t = out + (size_t)t * HT;
      auto body = [&](const f32x4 (&am)[2]) {
        float v[2][4];
#pragma unroll
        for (int jf = 0; jf < 2; ++jf)
#pragma unroll
          for (int r = 0; r < 4; ++r) {
            const int bl = q * 4 + r, jl = jf * 16 + ln;
            const float rec = am[jf][r] + red[par][0][mt][bl][jl]
                            + red[par][1][mt][bl][jl] + red[par][2][mt][bl][jl];
            float x = 0.9f * hcur[jf][r] + 0.1f * (rec + bj2[jf] + xcur[jf][r]);
            x = x > 0.f ? x : 0.f;
            v[jf][r] = x;
            hcur[jf][r] = x;
            __hip_atomic_store(&hnext[obase + (size_t)r * H_DIM + jf * 16],
                               f2bf(x), __ATOMIC_RELAXED,
                               __HIP_MEMORY_SCOPE_AGENT);
          }
        // Flag path: drain own WT h-stores (x prefetch is long done), post.
        asm volatile("s_waitcnt vmcnt(0)" ::: "memory");
        __builtin_amdgcn_sched_barrier(0);
        if (lane == 0)
          __hip_atomic_store(myflag, (unsigned)(t + 1), __ATOMIC_RELAXED,
                             __HIP_MEMORY_SCOPE_AGENT);
        // Off the flag path: fp32 outputs; rotate the x prefetch.
#pragma unroll
        for (int jf = 0; jf < 2; ++jf)
#pragma unroll
          for (int r = 0; r < 4; ++r) {
            xio_t[obase + (size_t)r * H_DIM + jf * 16] = v[jf][r];
            xcur[jf][r] = xnf[jf][r];
          }
      };
      if (kq == 0) body(acc[0]); else body(acc[1]);
    }
  }
}

// ---------------------------------------------------------------------------
extern "C" void kernel_launch(void* const* d_in, const int* in_sizes, int n_in,
                              void* d_out, int out_size, void* d_ws, size_t ws_size,
                              hipStream_t stream) {
  const float* input = (const float*)d_in[0];
  const float* W_in  = (const float*)d_in[1];
  const float* b_in  = (const float*)d_in[2];
  const float* W_hh  = (const float*)d_in[3];
  const float* b_hh  = (const float*)d_in[4];
  const float* h0    = (const float*)d_in[5];
  float* out = (float*)d_out;

  // ws layout (bytes):
  //   [0,  2M)   Wb   bf16 [1024][1024]
  //   [2M, 2.5M) hT   ping-pong 2 x 256 KB
  //   [2.5M,3M)  Wih  bf16-hi W_in ; [3M,3.5M) Wil bf16-lo
  //   [4M, 20M)  Ah   bf16-hi input ; [20M,36M) Al bf16-lo
  char* ws = (char*)d_ws;
  unsigned short* Wb  = (unsigned short*)ws;
  unsigned short* hT  = (unsigned short*)(ws + (2u << 20));
  unsigned short* Wih = (unsigned short*)(ws + (5u << 19));
  unsigned short* Wil = (unsigned short*)(ws + (3u << 20));
  unsigned short* Ah  = (unsigned short*)(ws + (4u << 20));
  unsigned short* Al  = (unsigned short*)(ws + (20u << 20));

  cvt_w_bf16<<<(H_DIM * H_DIM / 4) / 256, 256, 0, stream>>>(W_hh, Wb);
  init_hT0<<<(B_DIM * H_DIM) / 256, 256, 0, stream>>>(h0, hT);

  if (ws_size >= (36u << 20)) {
    cvt_hi_lo<<<(T_LEN * B_DIM * I_DIM / 4) / 256, 256, 0, stream>>>(input, Ah, Al);
    cvt_hi_lo<<<(H_DIM * I_DIM / 4) / 256, 256, 0, stream>>>(W_in, Wih, Wil);
    dim3 g1(H_DIM / 64, (T_LEN * B_DIM) / 128);
    xproj_mfma<<<g1, 256, 0, stream>>>(Ah, Al, Wih, Wil, b_in, out);
  } else {
    dim3 g1(H_DIM / 64, (T_LEN * B_DIM) / 64);
    xproj_gemm<<<g1, 256, 0, stream>>>(input, W_in, b_in, out);
  }

  {
    unsigned short* hT_ = hT;
    const unsigned short* Wb_ = Wb;
    const float* bhh_ = b_hh;
    const float* h0_ = h0;
    float* out_ = out;
    void* pargs[5] = {(void*)&hT_, (void*)&Wb_, (void*)&bhh_, (void*)&h0_, (void*)&out_};
    hipLaunchCooperativeKernel((const void*)rnn_persist, dim3(128), dim3(256),
                               pargs, 0, stream);
  }
}